// Round 10
// baseline (2785.946 us; speedup 1.0000x reference)
//
#include <hip/hip_runtime.h>
#include <cstddef>

#define S_LEN 256
#define H_DIM 512

typedef __attribute__((ext_vector_type(8))) short bf16x8;
typedef __attribute__((ext_vector_type(4))) float f32x4;
typedef __attribute__((ext_vector_type(8))) unsigned short u16x8;

__device__ __forceinline__ float sigf(float x) { return 1.0f / (1.0f + expf(-x)); }

__device__ __forceinline__ unsigned short cvt_bf16(float f) {
  unsigned u = __float_as_uint(f);
  u += 0x7fffu + ((u >> 16) & 1u);   // RNE (finite inputs)
  return (unsigned short)(u >> 16);
}
__device__ __forceinline__ float bf2f(unsigned short s) {
  return __uint_as_float(((unsigned)s) << 16);
}

// ---------------- zero init ----------------
__global__ void zero_kernel(float* __restrict__ p, int n4) {
  int i = blockIdx.x * blockDim.x + threadIdx.x;
  if (i < n4) ((float4*)p)[i] = make_float4(0.f, 0.f, 0.f, 0.f);
}

// ---------------- f32 -> bf16 bulk convert ----------------
__global__ __launch_bounds__(256)
void cvt_f32_bf16(const float* __restrict__ in, unsigned short* __restrict__ out,
                  int n4) {
  int i = blockIdx.x * blockDim.x + threadIdx.x;
  if (i < n4) {
    float4 v = ((const float4*)in)[i];
    ushort4 r;
    r.x = cvt_bf16(v.x); r.y = cvt_bf16(v.y);
    r.z = cvt_bf16(v.z); r.w = cvt_bf16(v.w);
    ((ushort4*)out)[i] = r;
  }
}

// ---------------- embedding + DyT -> bf16 ----------------
__global__ __launch_bounds__(128)
void embed_dyt(const int* __restrict__ idx, const float* __restrict__ E,
               const float* __restrict__ alpha_p, const float* __restrict__ gamma,
               const float* __restrict__ beta, unsigned short* __restrict__ out) {
  const int row = blockIdx.x;
  const int t4  = threadIdx.x * 4;
  const int id  = idx[row];
  const float al = alpha_p[0];
  float4 e = make_float4(0.f, 0.f, 0.f, 0.f);
  if (id != 0) e = *(const float4*)(E + (size_t)id * H_DIM + t4);
  const float4 g = *(const float4*)(gamma + t4);
  const float4 b = *(const float4*)(beta + t4);
  ushort4 o;
  o.x = cvt_bf16(g.x * tanhf(al * e.x) + b.x);
  o.y = cvt_bf16(g.y * tanhf(al * e.y) + b.y);
  o.z = cvt_bf16(g.z * tanhf(al * e.z) + b.z);
  o.w = cvt_bf16(g.w * tanhf(al * e.w) + b.w);
  *(ushort4*)(out + (size_t)row * H_DIM + t4) = o;
}

// ---- MFMA GEMM: C[M,N] f32 = A[M,K](bf16) . B[N,K](f32, cvt on the fly)^T + bias ----
template<int ZSKIP>
__global__ __launch_bounds__(256)
void gemm_bt_bf16(const unsigned short* __restrict__ A,
                  const float* __restrict__ Bf,
                  const float* __restrict__ bias,
                  float* __restrict__ C, int N, int K) {
  __shared__ unsigned short As[128 * 64];
  __shared__ unsigned short Bs[128 * 64];
  __shared__ int nzf[4];
  const int tid = threadIdx.x;
  const int bm = blockIdx.x * 128, bn = blockIdx.y * 128;
  const int lane = tid & 63;
  const int wr = (tid >> 7) & 1, wc = (tid >> 6) & 1;
  f32x4 acc[4][4] = {};

  const int srow = tid >> 3;
  const int ss   = tid & 7;

  for (int k0 = 0; k0 < K; k0 += 64) {
    __syncthreads();
    if (ZSKIP) {
      unsigned nz = 0u;
#pragma unroll
      for (int p = 0; p < 4; ++p) {
        const int row = srow + p * 32;
        const int ps = ss ^ (row & 7);
        u16x8 va = *(const u16x8*)(A + (size_t)(bm + row) * K + k0 + ss * 8);
        *(u16x8*)(As + row * 64 + ps * 8) = va;
#pragma unroll
        for (int j = 0; j < 8; ++j) nz |= (unsigned)(unsigned short)va[j];
      }
      const int wnz = __any(nz != 0u) ? 1 : 0;
      if ((tid & 63) == 0) nzf[tid >> 6] = wnz;
      __syncthreads();
      if ((nzf[0] | nzf[1] | nzf[2] | nzf[3]) == 0) continue;   // exact skip
#pragma unroll
      for (int p = 0; p < 4; ++p) {
        const int row = srow + p * 32;
        const int ps = ss ^ (row & 7);
        const float* bp = Bf + (size_t)(bn + row) * K + k0 + ss * 8;
        const float4 b0 = *(const float4*)(bp);
        const float4 b1 = *(const float4*)(bp + 4);
        u16x8 vb;
        vb[0] = cvt_bf16(b0.x); vb[1] = cvt_bf16(b0.y);
        vb[2] = cvt_bf16(b0.z); vb[3] = cvt_bf16(b0.w);
        vb[4] = cvt_bf16(b1.x); vb[5] = cvt_bf16(b1.y);
        vb[6] = cvt_bf16(b1.z); vb[7] = cvt_bf16(b1.w);
        *(u16x8*)(Bs + row * 64 + ps * 8) = vb;
      }
      __syncthreads();
    } else {
#pragma unroll
      for (int p = 0; p < 4; ++p) {
        const int row = srow + p * 32;
        const int ps = ss ^ (row & 7);
        u16x8 va = *(const u16x8*)(A + (size_t)(bm + row) * K + k0 + ss * 8);
        *(u16x8*)(As + row * 64 + ps * 8) = va;
        const float* bp = Bf + (size_t)(bn + row) * K + k0 + ss * 8;
        const float4 b0 = *(const float4*)(bp);
        const float4 b1 = *(const float4*)(bp + 4);
        u16x8 vb;
        vb[0] = cvt_bf16(b0.x); vb[1] = cvt_bf16(b0.y);
        vb[2] = cvt_bf16(b0.z); vb[3] = cvt_bf16(b0.w);
        vb[4] = cvt_bf16(b1.x); vb[5] = cvt_bf16(b1.y);
        vb[6] = cvt_bf16(b1.z); vb[7] = cvt_bf16(b1.w);
        *(u16x8*)(Bs + row * 64 + ps * 8) = vb;
      }
      __syncthreads();
    }
#pragma unroll
    for (int ks = 0; ks < 2; ++ks) {
      const int r16 = lane & 15;
      const int kslot = ks * 4 + (lane >> 4);
      bf16x8 af[4], bfr[4];
#pragma unroll
      for (int m = 0; m < 4; ++m) {
        const int row = wr * 64 + m * 16 + r16;
        af[m] = *(const bf16x8*)(As + row * 64 + (kslot ^ (row & 7)) * 8);
      }
#pragma unroll
      for (int n = 0; n < 4; ++n) {
        const int row = wc * 64 + n * 16 + r16;
        bfr[n] = *(const bf16x8*)(Bs + row * 64 + (kslot ^ (row & 7)) * 8);
      }
#pragma unroll
      for (int m = 0; m < 4; ++m)
#pragma unroll
        for (int n = 0; n < 4; ++n)
          acc[m][n] = __builtin_amdgcn_mfma_f32_16x16x32_bf16(af[m], bfr[n],
                                                              acc[m][n], 0, 0, 0);
    }
  }

  const int r16 = lane & 15, rg = lane >> 4;
#pragma unroll
  for (int m = 0; m < 4; ++m) {
#pragma unroll
    for (int n = 0; n < 4; ++n) {
      const int col = bn + wc * 64 + n * 16 + r16;
      const float bb = bias[col];
      const int rowb = bm + wr * 64 + m * 16 + rg * 4;
#pragma unroll
      for (int r = 0; r < 4; ++r)
        C[(size_t)(rowb + r) * N + col] = acc[m][n][r] + bb;
    }
  }
}

// ---------------- persistent encoder (relaxed-atomic flag channel) ----------------
// 2 independent chains x 64 WGs. WG g owns h cols [8g,8g+8).
// Channel design (r2/r3/r5 post-mortems): relaxed agent atomics only (proven
// promptly cross-XCD coherent), per-WG flag words (low contention), s_sleep
// backoff, vmcnt(0) for h-store -> flag-store ordering. No acquire/release in
// the hot loop. Budget-capped: can produce a wrong answer, can never hang.
struct EncP {
  const float* xg;                 // [(b*256+t)*4096 + grow]
  const unsigned short* Whh;       // bf16 [2048,512]
  const float* bhh;
  float* ring;                     // [2][2048]
  int* flags;                      // [64]
  float* cfin;                     // [2048] final c out
};

__global__ __launch_bounds__(256)
void enc_persist(EncP P0, EncP P1) {
  const EncP P = (blockIdx.x < 64) ? P0 : P1;
  const int g = blockIdx.x & 63;
  const int tid = threadIdx.x;
  __shared__ float hs[2048];
  __shared__ float gred[32][4];
  __shared__ float cst[32];
  const int lr = tid >> 3, kc = tid & 7;
  const int q = lr >> 3, ci = lr & 7;
  const int c0 = g * 8;
  const int grow = q * H_DIM + c0 + ci;
  // weights resident in VGPRs: 8 x u16x8 = 64 bf16 per lane
  u16x8 w[8];
  {
    const unsigned short* wrow = P.Whh + (size_t)grow * H_DIM + kc * 8;
#pragma unroll
    for (int it = 0; it < 8; ++it) w[it] = *(const u16x8*)(wrow + it * 64);
  }
  const float bb = P.bhh[grow];
  const float* xgp = P.xg + grow;
  if (tid < 32) cst[tid] = 0.f;   // c0 = 0
  int budget = 2000000;

  for (int t = 0; t < 256; ++t) {
    float xgv[4] = {0.f, 0.f, 0.f, 0.f};
    if (kc == 0) {
#pragma unroll
      for (int b = 0; b < 4; ++b)
        xgv[b] = xgp[(size_t)(b * S_LEN + t) * 4096];
    }
    if (t == 0) {
#pragma unroll
      for (int j = 0; j < 8; ++j) hs[j * 256 + tid] = 0.f;   // h0 = 0
    } else {
      if (tid < 64) {
        const int* fp = P.flags + tid;
        while (budget > 0) {
          int v = __hip_atomic_load(fp, __ATOMIC_RELAXED, __HIP_MEMORY_SCOPE_AGENT);
          if (v >= t) break;
          __builtin_amdgcn_s_sleep(1);
          --budget;
        }
      }
      __syncthreads();
      const float* slot = P.ring + (size_t)(t & 1) * 2048;
#pragma unroll
      for (int j = 0; j < 8; ++j)
        hs[j * 256 + tid] = __hip_atomic_load(slot + j * 256 + tid,
                                              __ATOMIC_RELAXED,
                                              __HIP_MEMORY_SCOPE_AGENT);
    }
    __syncthreads();

    float acc[4] = {0.f, 0.f, 0.f, 0.f};
#pragma unroll
    for (int it = 0; it < 8; ++it) {
      const int k = it * 64 + kc * 8;
      const u16x8 wv = w[it];
      const float w0 = bf2f(wv[0]), w1 = bf2f(wv[1]), w2 = bf2f(wv[2]), w3 = bf2f(wv[3]);
      const float w4 = bf2f(wv[4]), w5 = bf2f(wv[5]), w6 = bf2f(wv[6]), w7 = bf2f(wv[7]);
#pragma unroll
      for (int b = 0; b < 4; ++b) {
        const float4 hA = *(const float4*)&hs[b * H_DIM + k];
        const float4 hB = *(const float4*)&hs[b * H_DIM + k + 4];
        acc[b] += w0 * hA.x + w1 * hA.y + w2 * hA.z + w3 * hA.w
                + w4 * hB.x + w5 * hB.y + w6 * hB.z + w7 * hB.w;
      }
    }
#pragma unroll
    for (int off = 1; off < 8; off <<= 1) {
#pragma unroll
      for (int b = 0; b < 4; ++b) acc[b] += __shfl_xor(acc[b], off);
    }
    if (kc == 0) {
#pragma unroll
      for (int b = 0; b < 4; ++b) gred[lr][b] = acc[b] + xgv[b] + bb;
    }
    __syncthreads();

    if (tid < 32) {
      const int b = tid & 3, cc = tid >> 2;
      const int col = c0 + cc;
      const float gi = gred[cc][b];
      const float gf = gred[8 + cc][b];
      const float gg = gred[16 + cc][b];
      const float go = gred[24 + cc][b];
      const float cold = cst[tid];
      const float cn = sigf(gf) * cold + sigf(gi) * tanhf(gg);
      const float hn = sigf(go) * tanhf(cn);
      cst[tid] = cn;
      __hip_atomic_store(P.ring + (size_t)((t + 1) & 1) * 2048 + b * H_DIM + col,
                         hn, __ATOMIC_RELAXED, __HIP_MEMORY_SCOPE_AGENT);
      if (t == 255) P.cfin[b * H_DIM + col] = cn;
    }
    asm volatile("s_waitcnt vmcnt(0)" ::: "memory");   // h stores at coherence point
    __syncthreads();
    if (tid == 0)
      __hip_atomic_store(P.flags + g, t + 1, __ATOMIC_RELAXED,
                         __HIP_MEMORY_SCOPE_AGENT);
  }
}

// ---------------- shared recurrent-step core (decoder slots, r9-proven) ----------
__device__ __forceinline__ void rec_core(
    int g, int t, int tid,
    const float* __restrict__ xg, int xg_stride,
    const unsigned short* __restrict__ Whh, const float* __restrict__ bhh,
    const float* __restrict__ h_in, float* __restrict__ h_out,
    float* __restrict__ c,
    float* __restrict__ spk, const float* __restrict__ thr,
    float* __restrict__ hs, float (*__restrict__ gred)[4]) {
  const int lr = tid >> 3, kc = tid & 7;
  const int q = lr >> 3, ci = lr & 7;
  const int c0 = g * 8;
  const int grow = q * H_DIM + c0 + ci;
  float xgv[4] = {0.f, 0.f, 0.f, 0.f};
  if (kc == 0) {
#pragma unroll
    for (int b = 0; b < 4; ++b)
      xgv[b] = xg[(size_t)(b * S_LEN + t) * xg_stride + grow];
  }
  {
    const float4* s4 = (const float4*)h_in;
    float4* d4 = (float4*)hs;
    d4[tid] = s4[tid];
    d4[tid + 256] = s4[tid + 256];
  }
  __syncthreads();
  const unsigned short* wrow = Whh + (size_t)grow * H_DIM;
  float acc[4] = {0.f, 0.f, 0.f, 0.f};
#pragma unroll
  for (int it = 0; it < 8; ++it) {
    const int k = it * 64 + kc * 8;
    const u16x8 wv = *(const u16x8*)(wrow + k);
    const float w0 = bf2f(wv[0]), w1 = bf2f(wv[1]), w2 = bf2f(wv[2]), w3 = bf2f(wv[3]);
    const float w4 = bf2f(wv[4]), w5 = bf2f(wv[5]), w6 = bf2f(wv[6]), w7 = bf2f(wv[7]);
#pragma unroll
    for (int b = 0; b < 4; ++b) {
      const float4 hA = *(const float4*)&hs[b * H_DIM + k];
      const float4 hB = *(const float4*)&hs[b * H_DIM + k + 4];
      acc[b] += w0 * hA.x + w1 * hA.y + w2 * hA.z + w3 * hA.w
              + w4 * hB.x + w5 * hB.y + w6 * hB.z + w7 * hB.w;
    }
  }
#pragma unroll
  for (int off = 1; off < 8; off <<= 1) {
#pragma unroll
    for (int b = 0; b < 4; ++b) acc[b] += __shfl_xor(acc[b], off);
  }
  if (kc == 0) {
    const float bb = bhh[grow];
#pragma unroll
    for (int b = 0; b < 4; ++b) gred[lr][b] = acc[b] + xgv[b] + bb;
  }
  __syncthreads();
  if (tid < 32) {
    const int b = tid & 3, cc = tid >> 2;
    const int col = c0 + cc;
    const float gi = gred[cc][b];
    const float gf = gred[8 + cc][b];
    const float gg = gred[16 + cc][b];
    const float go = gred[24 + cc][b];
    const float cold = c[b * H_DIM + col];
    const float cn = sigf(gf) * cold + sigf(gi) * tanhf(gg);
    const float hn = sigf(go) * tanhf(cn);
    c[b * H_DIM + col] = cn;
    h_out[b * H_DIM + col] = hn;
    if (spk)
      spk[(size_t)(b * S_LEN + t) * H_DIM + col] = (hn - thr[col]) > 0.f ? 1.f : 0.f;
  }
}

// ---------------- pipelined decoder slot (5 roles, r7/r9-proven) ----------------
struct DecArgs {
  const float* xg0;
  float*       xg1;
  const unsigned short* Whh0bf; const unsigned short* Whh1bf;
  const float* bhh0; const float* bhh1;
  const unsigned short* Wih1bf; const float* bih1;
  const float* fc0W; const float* fc0b;
  const float* fc1W; const float* fc1b;
  const float* dyt_a;
  const float* dyt_g;
  const float* dyt_b;
  const float* thr0; const float* thr1;
  float* c0; float* c1;
  const float* h0_init; const float* h1_init;
  float* ring0; float* ring1;
  float* spk0; float* spk1;
  float* x1;
  unsigned short* x2;
};

__device__ __forceinline__ void stage_rows(const float* __restrict__ src, int t,
                                           int tid, float* dst) {
  float4* d4 = (float4*)dst;
  const int f0 = tid, f1 = tid + 256;
  d4[f0] = *(const float4*)(src + (size_t)((f0 >> 7) * S_LEN + t) * H_DIM + (f0 & 127) * 4);
  d4[f1] = *(const float4*)(src + (size_t)((f1 >> 7) * S_LEN + t) * H_DIM + (f1 & 127) * 4);
}

__global__ __launch_bounds__(256)
void dec_slot(DecArgs A, int s) {
  __shared__ float hs[4 * H_DIM];
  __shared__ float gred[32][4];
  const int bid = blockIdx.x;
  const int tid = threadIdx.x;

  if (bid < 64) {
    const int t = s;
    if (t < 256) {
      const float* h_in = (t == 0) ? A.h0_init : (A.ring0 + (size_t)(t & 1) * 2048);
      float* h_out = A.ring0 + (size_t)((t + 1) & 1) * 2048;
      rec_core(bid, t, tid, A.xg0, 2048, A.Whh0bf, A.bhh0, h_in, h_out, A.c0,
               A.spk0, A.thr0, hs, gred);
    }
  } else if (bid < 128) {
    const int t = s - 3;
    if (t >= 0 && t < 256) {
      const float* h_in = (t == 0) ? A.h1_init : (A.ring1 + (size_t)(t & 1) * 2048);
      float* h_out = A.ring1 + (size_t)((t + 1) & 1) * 2048;
      rec_core(bid - 64, t, tid, A.xg1, 2048, A.Whh1bf, A.bhh1, h_in, h_out, A.c1,
               A.spk1, A.thr1, hs, gred);
    }
  } else if (bid < 192) {
    const int t = s - 2;
    if (t >= 0 && t < 256) {
      stage_rows(A.x1, t, tid, hs);
      __syncthreads();
      const int wc = bid - 128;
      const int lr = tid >> 3, kc = tid & 7;
      const int row = wc * 32 + lr;
      const unsigned short* wrow = A.Wih1bf + (size_t)row * H_DIM;
      float acc[4] = {0.f, 0.f, 0.f, 0.f};
#pragma unroll
      for (int it = 0; it < 8; ++it) {
        const int k = it * 64 + kc * 8;
        const u16x8 wv = *(const u16x8*)(wrow + k);
        const float w0 = bf2f(wv[0]), w1 = bf2f(wv[1]), w2 = bf2f(wv[2]), w3 = bf2f(wv[3]);
        const float w4 = bf2f(wv[4]), w5 = bf2f(wv[5]), w6 = bf2f(wv[6]), w7 = bf2f(wv[7]);
#pragma unroll
        for (int b = 0; b < 4; ++b) {
          const float4 hA = *(const float4*)&hs[b * H_DIM + k];
          const float4 hB = *(const float4*)&hs[b * H_DIM + k + 4];
          acc[b] += w0 * hA.x + w1 * hA.y + w2 * hA.z + w3 * hA.w
                  + w4 * hB.x + w5 * hB.y + w6 * hB.z + w7 * hB.w;
        }
      }
#pragma unroll
      for (int off = 1; off < 8; off <<= 1) {
#pragma unroll
        for (int b = 0; b < 4; ++b) acc[b] += __shfl_xor(acc[b], off);
      }
      if (kc == 0) {
        const float bb = A.bih1[row];
#pragma unroll
        for (int b = 0; b < 4; ++b)
          A.xg1[(size_t)(b * S_LEN + t) * 2048 + row] = acc[b] + bb;
      }
    }
  } else {
    const bool isB = (bid < 224);
    const int t = isB ? (s - 1) : (s - 4);
    if (t >= 0 && t < 256) {
      const float* spk = isB ? A.spk0 : A.spk1;
      const float* fcW = isB ? A.fc0W : A.fc1W;
      const float* fcb = isB ? A.fc0b : A.fc1b;
      const int lidx = isB ? 0 : 1;
      stage_rows(spk, t, tid, hs);
      __syncthreads();
      const int wb = bid - (isB ? 192 : 224);
      const int lr = tid >> 4, kc = tid & 15;
      const int col = wb * 16 + lr;
      const float* wrow = fcW + (size_t)col * H_DIM;
      float a0 = 0.f, a1 = 0.f, a2 = 0.f, a3 = 0.f;
#pragma unroll
      for (int it = 0; it < 8; ++it) {
        const int k = kc * 32 + it * 4;
        const float4 w  = *(const float4*)(wrow + k);
        const float4 h0 = *(const float4*)&hs[0 * H_DIM + k];
        const float4 h1 = *(const float4*)&hs[1 * H_DIM + k];
        const float4 h2 = *(const float4*)&hs[2 * H_DIM + k];
        const float4 h3 = *(const float4*)&hs[3 * H_DIM + k];
        a0 += w.x * h0.x + w.y * h0.y + w.z * h0.z + w.w * h0.w;
        a1 += w.x * h1.x + w.y * h1.y + w.z * h1.z + w.w * h1.w;
        a2 += w.x * h2.x + w.y * h2.y + w.z * h2.z + w.w * h2.w;
        a3 += w.x * h3.x + w.y * h3.y + w.z * h3.z + w.w * h3.w;
      }
#pragma unroll
      for (int off = 1; off < 16; off <<= 1) {
        a0 += __shfl_xor(a0, off);
        a1 += __shfl_xor(a1, off);
        a2 += __shfl_xor(a2, off);
        a3 += __shfl_xor(a3, off);
      }
      if (kc == 0) {
        const float al = A.dyt_a[lidx];
        const float gm = A.dyt_g[lidx * H_DIM + col];
        const float be = A.dyt_b[lidx * H_DIM + col];
        const float bb = fcb[col];
        float v[4] = {a0, a1, a2, a3};
#pragma unroll
        for (int b = 0; b < 4; ++b) {
          float y = v[b] + bb;
          if (!isB) y += A.x1[(size_t)(b * S_LEN + t) * H_DIM + col];
          const float r = gm * tanhf(al * y) + be;
          if (isB) A.x1[(size_t)(b * S_LEN + t) * H_DIM + col] = r;
          else     A.x2[(size_t)(b * S_LEN + t) * H_DIM + col] = cvt_bf16(r);
        }
      }
    }
  }
}

extern "C" void kernel_launch(void* const* d_in, const int* in_sizes, int n_in,
                              void* d_out, int out_size, void* d_ws, size_t ws_size,
                              hipStream_t stream) {
  (void)in_sizes; (void)n_in; (void)out_size; (void)ws_size;
  const int*   src       = (const int*)d_in[0];
  const int*   tgt       = (const int*)d_in[1];
  const float* emb_enc   = (const float*)d_in[2];
  const float* enc_alpha = (const float*)d_in[3];
  const float* enc_gamma = (const float*)d_in[4];
  const float* enc_beta  = (const float*)d_in[5];
  const float* enc_Wih   = (const float*)d_in[6];
  const float* enc_Whh   = (const float*)d_in[7];
  const float* enc_bih   = (const float*)d_in[8];
  const float* enc_bhh   = (const float*)d_in[9];
  const float* emb_dec   = (const float*)d_in[11];
  const float* dec_alpha = (const float*)d_in[12];
  const float* dec_gamma = (const float*)d_in[13];
  const float* dec_beta  = (const float*)d_in[14];
  const float* dec_Wih   = (const float*)d_in[15];
  const float* dec_Whh   = (const float*)d_in[16];
  const float* dec_bih   = (const float*)d_in[17];
  const float* dec_bhh   = (const float*)d_in[18];
  const float* dec_thr   = (const float*)d_in[19];
  const float* dec_fc_W  = (const float*)d_in[20];
  const float* dec_fc_b  = (const float*)d_in[21];
  const float* dyt_alpha = (const float*)d_in[22];
  const float* dyt_gamma = (const float*)d_in[23];
  const float* dyt_beta  = (const float*)d_in[24];
  const float* out_W     = (const float*)d_in[25];
  const float* out_b     = (const float*)d_in[26];
  float* out = (float*)d_out;

  float* ws = (float*)d_ws;
  float*          x1        = ws;                                 // [1024,512] f32
  float*          xg_enc    = ws + 524288;                        // [1024,4096] f32
  float*          xg_d0     = xg_enc;                             // overlay after enc
  float*          xg_d1     = xg_enc + 2097152;                   // [1024,2048]
  float*          spk0      = ws + 4718592;                       // [1024,512]
  float*          spk1      = ws + 5242880;                       // [1024,512]
  unsigned short* src_e_bf  = (unsigned short*)(ws + 5767168);    // [1024,512] bf16
  unsigned short* dec_x0_bf = (unsigned short*)(ws + 5898240);    // [1024,512] bf16
  unsigned short* x2_bf     = (unsigned short*)(ws + 6029312);    // [1024,512] bf16
  unsigned short* wbf       = (unsigned short*)(ws + 6160384);    // up to 3M bf16
  float* st = ws + 7660544;
  float* zbuf    = st;                       // [2048] zeros (unused slack)
  float* c0buf   = st + 2048;
  float* c1buf   = st + 4096;
  int*   iflags  = (int*)(st + 6144);        // 128 flags (2 chains x 64)
  float* ring_e0 = st + 6272;                // [2][2048]
  float* ring_e1 = st + 10368;
  float* ring_d0 = st + 14464;
  float* ring_d1 = st + 18560;               // end st+22656

  (void)zbuf;
  // zero zbuf + c bufs + flags (6272 floats -> 1568 float4)
  zero_kernel<<<7, 256, 0, stream>>>(st, 1568);
  embed_dyt<<<1024, 128, 0, stream>>>(src, emb_enc, enc_alpha, enc_gamma, enc_beta,
                                      src_e_bf);
  embed_dyt<<<1024, 128, 0, stream>>>(tgt, emb_dec, dec_alpha, dec_gamma, dec_beta,
                                      dec_x0_bf);

  // enc Whh (both layers) -> bf16
  cvt_f32_bf16<<<2048, 256, 0, stream>>>(enc_Whh, wbf, 524288);

  // Encoder xg (both layers stacked [4096,512]) via bf16 MFMA
  gemm_bt_bf16<0><<<dim3(8, 32), 256, 0, stream>>>(src_e_bf, enc_Wih, enc_bih,
                                                   xg_enc, 4096, 512);

  // Encoder recurrence: ONE persistent dispatch (128 WGs, 2 chains)
  EncP E0, E1;
  E0.xg = xg_enc;        E0.Whh = wbf;            E0.bhh = enc_bhh;
  E0.ring = ring_e0;     E0.flags = iflags;       E0.cfin = c0buf;
  E1.xg = xg_enc + 2048; E1.Whh = wbf + 1048576;  E1.bhh = enc_bhh + 2048;
  E1.ring = ring_e1;     E1.flags = iflags + 64;  E1.cfin = c1buf;
  enc_persist<<<128, 256, 0, stream>>>(E0, E1);
  // final enc h(256) = ring_e{l} parity 0; final c in c{l}buf

  // dec weights -> bf16 (reuse wbf; stream-ordered after enc)
  cvt_f32_bf16<<<2048, 256, 0, stream>>>(dec_Whh, wbf, 524288);
  cvt_f32_bf16<<<1024, 256, 0, stream>>>(dec_Wih + 1048576, wbf + 2097152, 262144);

  // Decoder layer0 xg via bf16 MFMA (overwrites xg_enc region)
  gemm_bt_bf16<0><<<dim3(8, 16), 256, 0, stream>>>(dec_x0_bf, dec_Wih, dec_bih,
                                                   xg_d0, 2048, 512);

  DecArgs D;
  D.xg0 = xg_d0;              D.xg1 = xg_d1;
  D.Whh0bf = wbf;             D.Whh1bf = wbf + 1048576;
  D.bhh0 = dec_bhh;           D.bhh1 = dec_bhh + 2048;
  D.Wih1bf = wbf + 2097152;   D.bih1 = dec_bih + 2048;
  D.fc0W = dec_fc_W;          D.fc0b = dec_fc_b;
  D.fc1W = dec_fc_W + 262144; D.fc1b = dec_fc_b + 512;
  D.dyt_a = dyt_alpha;        D.dyt_g = dyt_gamma;     D.dyt_b = dyt_beta;
  D.thr0 = dec_thr;           D.thr1 = dec_thr + 512;
  D.c0 = c0buf;               D.c1 = c1buf;
  D.h0_init = ring_e0;        D.h1_init = ring_e1;     // parity-0 halves
  D.ring0 = ring_d0;          D.ring1 = ring_d1;
  D.spk0 = spk0;              D.spk1 = spk1;
  D.x1 = x1;                  D.x2 = x2_bf;

  for (int s = 0; s < 260; ++s)
    dec_slot<<<256, 256, 0, stream>>>(D, s);

  // Output projection with exact A-tile zero-skip
  gemm_bt_bf16<1><<<dim3(8, 250), 256, 0, stream>>>(x2_bf, out_W, out_b,
                                                    out, 32000, 512);
}

// Round 11
// 2518.548 us; speedup vs baseline: 1.1062x; 1.1062x over previous
//
#include <hip/hip_runtime.h>
#include <cstddef>

#define S_LEN 256
#define H_DIM 512

typedef __attribute__((ext_vector_type(8))) short bf16x8;
typedef __attribute__((ext_vector_type(4))) float f32x4;
typedef __attribute__((ext_vector_type(8))) unsigned short u16x8;

__device__ __forceinline__ float sigf(float x) { return 1.0f / (1.0f + expf(-x)); }

__device__ __forceinline__ unsigned short cvt_bf16(float f) {
  unsigned u = __float_as_uint(f);
  u += 0x7fffu + ((u >> 16) & 1u);   // RNE (finite inputs)
  return (unsigned short)(u >> 16);
}
__device__ __forceinline__ float bf2f(unsigned short s) {
  return __uint_as_float(((unsigned)s) << 16);
}

// ---------------- zero init ----------------
__global__ void zero_kernel(float* __restrict__ p, int n4) {
  int i = blockIdx.x * blockDim.x + threadIdx.x;
  if (i < n4) ((float4*)p)[i] = make_float4(0.f, 0.f, 0.f, 0.f);
}

// ---------------- f32 -> bf16 bulk convert (two regions, one dispatch) --------
__global__ __launch_bounds__(256)
void cvt_f32_bf16_2(const float* __restrict__ inA, unsigned short* __restrict__ outA,
                    int n4A,
                    const float* __restrict__ inB, unsigned short* __restrict__ outB,
                    int n4B) {
  int i = blockIdx.x * blockDim.x + threadIdx.x;
  const float* in = inA;
  unsigned short* out = outA;
  if (i >= n4A) { i -= n4A; in = inB; out = outB; if (i >= n4B) return; }
  float4 v = ((const float4*)in)[i];
  ushort4 r;
  r.x = cvt_bf16(v.x); r.y = cvt_bf16(v.y);
  r.z = cvt_bf16(v.z); r.w = cvt_bf16(v.w);
  ((ushort4*)out)[i] = r;
}

__global__ __launch_bounds__(256)
void cvt_f32_bf16(const float* __restrict__ in, unsigned short* __restrict__ out,
                  int n4) {
  int i = blockIdx.x * blockDim.x + threadIdx.x;
  if (i < n4) {
    float4 v = ((const float4*)in)[i];
    ushort4 r;
    r.x = cvt_bf16(v.x); r.y = cvt_bf16(v.y);
    r.z = cvt_bf16(v.z); r.w = cvt_bf16(v.w);
    ((ushort4*)out)[i] = r;
  }
}

// ---------------- embedding + DyT -> bf16 ----------------
__global__ __launch_bounds__(128)
void embed_dyt(const int* __restrict__ idx, const float* __restrict__ E,
               const float* __restrict__ alpha_p, const float* __restrict__ gamma,
               const float* __restrict__ beta, unsigned short* __restrict__ out) {
  const int row = blockIdx.x;
  const int t4  = threadIdx.x * 4;
  const int id  = idx[row];
  const float al = alpha_p[0];
  float4 e = make_float4(0.f, 0.f, 0.f, 0.f);
  if (id != 0) e = *(const float4*)(E + (size_t)id * H_DIM + t4);
  const float4 g = *(const float4*)(gamma + t4);
  const float4 b = *(const float4*)(beta + t4);
  ushort4 o;
  o.x = cvt_bf16(g.x * tanhf(al * e.x) + b.x);
  o.y = cvt_bf16(g.y * tanhf(al * e.y) + b.y);
  o.z = cvt_bf16(g.z * tanhf(al * e.z) + b.z);
  o.w = cvt_bf16(g.w * tanhf(al * e.w) + b.w);
  *(ushort4*)(out + (size_t)row * H_DIM + t4) = o;
}

// ---- MFMA GEMM: C[M,N] f32 = A[M,K](bf16) . B[N,K](f32, cvt on the fly)^T + bias ----
// ZSKIP=1: per-(block,K-step) A-tile zero check; zero tile contributes exactly 0.
template<int ZSKIP>
__global__ __launch_bounds__(256)
void gemm_bt_bf16(const unsigned short* __restrict__ A,
                  const float* __restrict__ Bf,
                  const float* __restrict__ bias,
                  float* __restrict__ C, int N, int K) {
  __shared__ unsigned short As[128 * 64];
  __shared__ unsigned short Bs[128 * 64];
  __shared__ int nzf[4];
  const int tid = threadIdx.x;
  const int bm = blockIdx.x * 128, bn = blockIdx.y * 128;
  const int lane = tid & 63;
  const int wr = (tid >> 7) & 1, wc = (tid >> 6) & 1;
  f32x4 acc[4][4] = {};

  const int srow = tid >> 3;
  const int ss   = tid & 7;

  for (int k0 = 0; k0 < K; k0 += 64) {
    __syncthreads();
    if (ZSKIP) {
      unsigned nz = 0u;
#pragma unroll
      for (int p = 0; p < 4; ++p) {
        const int row = srow + p * 32;
        const int ps = ss ^ (row & 7);
        u16x8 va = *(const u16x8*)(A + (size_t)(bm + row) * K + k0 + ss * 8);
        *(u16x8*)(As + row * 64 + ps * 8) = va;
#pragma unroll
        for (int j = 0; j < 8; ++j) nz |= (unsigned)(unsigned short)va[j];
      }
      const int wnz = __any(nz != 0u) ? 1 : 0;
      if ((tid & 63) == 0) nzf[tid >> 6] = wnz;
      __syncthreads();
      if ((nzf[0] | nzf[1] | nzf[2] | nzf[3]) == 0) continue;   // exact skip
#pragma unroll
      for (int p = 0; p < 4; ++p) {
        const int row = srow + p * 32;
        const int ps = ss ^ (row & 7);
        const float* bp = Bf + (size_t)(bn + row) * K + k0 + ss * 8;
        const float4 b0 = *(const float4*)(bp);
        const float4 b1 = *(const float4*)(bp + 4);
        u16x8 vb;
        vb[0] = cvt_bf16(b0.x); vb[1] = cvt_bf16(b0.y);
        vb[2] = cvt_bf16(b0.z); vb[3] = cvt_bf16(b0.w);
        vb[4] = cvt_bf16(b1.x); vb[5] = cvt_bf16(b1.y);
        vb[6] = cvt_bf16(b1.z); vb[7] = cvt_bf16(b1.w);
        *(u16x8*)(Bs + row * 64 + ps * 8) = vb;
      }
      __syncthreads();
    } else {
#pragma unroll
      for (int p = 0; p < 4; ++p) {
        const int row = srow + p * 32;
        const int ps = ss ^ (row & 7);
        u16x8 va = *(const u16x8*)(A + (size_t)(bm + row) * K + k0 + ss * 8);
        *(u16x8*)(As + row * 64 + ps * 8) = va;
        const float* bp = Bf + (size_t)(bn + row) * K + k0 + ss * 8;
        const float4 b0 = *(const float4*)(bp);
        const float4 b1 = *(const float4*)(bp + 4);
        u16x8 vb;
        vb[0] = cvt_bf16(b0.x); vb[1] = cvt_bf16(b0.y);
        vb[2] = cvt_bf16(b0.z); vb[3] = cvt_bf16(b0.w);
        vb[4] = cvt_bf16(b1.x); vb[5] = cvt_bf16(b1.y);
        vb[6] = cvt_bf16(b1.z); vb[7] = cvt_bf16(b1.w);
        *(u16x8*)(Bs + row * 64 + ps * 8) = vb;
      }
      __syncthreads();
    }
#pragma unroll
    for (int ks = 0; ks < 2; ++ks) {
      const int r16 = lane & 15;
      const int kslot = ks * 4 + (lane >> 4);
      bf16x8 af[4], bfr[4];
#pragma unroll
      for (int m = 0; m < 4; ++m) {
        const int row = wr * 64 + m * 16 + r16;
        af[m] = *(const bf16x8*)(As + row * 64 + (kslot ^ (row & 7)) * 8);
      }
#pragma unroll
      for (int n = 0; n < 4; ++n) {
        const int row = wc * 64 + n * 16 + r16;
        bfr[n] = *(const bf16x8*)(Bs + row * 64 + (kslot ^ (row & 7)) * 8);
      }
#pragma unroll
      for (int m = 0; m < 4; ++m)
#pragma unroll
        for (int n = 0; n < 4; ++n)
          acc[m][n] = __builtin_amdgcn_mfma_f32_16x16x32_bf16(af[m], bfr[n],
                                                              acc[m][n], 0, 0, 0);
    }
  }

  const int r16 = lane & 15, rg = lane >> 4;
#pragma unroll
  for (int m = 0; m < 4; ++m) {
#pragma unroll
    for (int n = 0; n < 4; ++n) {
      const int col = bn + wc * 64 + n * 16 + r16;
      const float bb = bias[col];
      const int rowb = bm + wr * 64 + m * 16 + rg * 4;
#pragma unroll
      for (int r = 0; r < 4; ++r)
        C[(size_t)(rowb + r) * N + col] = acc[m][n][r] + bb;
    }
  }
}

// ---------------- shared recurrent-step core (bf16 weights, xg from global) ----
__device__ __forceinline__ void rec_core(
    int g, int t, int tid,
    const float* __restrict__ xg, int xg_stride,
    const unsigned short* __restrict__ Whh, const float* __restrict__ bhh,
    const float* __restrict__ h_in, float* __restrict__ h_out,
    float* __restrict__ c,
    float* __restrict__ spk, const float* __restrict__ thr,
    float* __restrict__ hs, float (*__restrict__ gred)[4]) {
  const int lr = tid >> 3, kc = tid & 7;
  const int q = lr >> 3, ci = lr & 7;
  const int c0 = g * 8;
  const int grow = q * H_DIM + c0 + ci;
  float xgv[4] = {0.f, 0.f, 0.f, 0.f};
  if (kc == 0) {
#pragma unroll
    for (int b = 0; b < 4; ++b)
      xgv[b] = xg[(size_t)(b * S_LEN + t) * xg_stride + grow];
  }
  {
    const float4* s4 = (const float4*)h_in;
    float4* d4 = (float4*)hs;
    d4[tid] = s4[tid];
    d4[tid + 256] = s4[tid + 256];
  }
  __syncthreads();
  const unsigned short* wrow = Whh + (size_t)grow * H_DIM;
  float acc[4] = {0.f, 0.f, 0.f, 0.f};
#pragma unroll
  for (int it = 0; it < 8; ++it) {
    const int k = it * 64 + kc * 8;
    const u16x8 wv = *(const u16x8*)(wrow + k);
    const float w0 = bf2f(wv[0]), w1 = bf2f(wv[1]), w2 = bf2f(wv[2]), w3 = bf2f(wv[3]);
    const float w4 = bf2f(wv[4]), w5 = bf2f(wv[5]), w6 = bf2f(wv[6]), w7 = bf2f(wv[7]);
#pragma unroll
    for (int b = 0; b < 4; ++b) {
      const float4 hA = *(const float4*)&hs[b * H_DIM + k];
      const float4 hB = *(const float4*)&hs[b * H_DIM + k + 4];
      acc[b] += w0 * hA.x + w1 * hA.y + w2 * hA.z + w3 * hA.w
              + w4 * hB.x + w5 * hB.y + w6 * hB.z + w7 * hB.w;
    }
  }
#pragma unroll
  for (int off = 1; off < 8; off <<= 1) {
#pragma unroll
    for (int b = 0; b < 4; ++b) acc[b] += __shfl_xor(acc[b], off);
  }
  if (kc == 0) {
    const float bb = bhh[grow];
#pragma unroll
    for (int b = 0; b < 4; ++b) gred[lr][b] = acc[b] + xgv[b] + bb;
  }
  __syncthreads();
  if (tid < 32) {
    const int b = tid & 3, cc = tid >> 2;
    const int col = c0 + cc;
    const float gi = gred[cc][b];
    const float gf = gred[8 + cc][b];
    const float gg = gred[16 + cc][b];
    const float go = gred[24 + cc][b];
    const float cold = c[b * H_DIM + col];
    const float cn = sigf(gf) * cold + sigf(gi) * tanhf(gg);
    const float hn = sigf(go) * tanhf(cn);
    c[b * H_DIM + col] = cn;
    h_out[b * H_DIM + col] = hn;
    if (spk)
      spk[(size_t)(b * S_LEN + t) * H_DIM + col] = (hn - thr[col]) > 0.f ? 1.f : 0.f;
  }
}

// ---------------- encoder per-step kernel ----------------
struct StepInst {
  const float* xg;
  const unsigned short* Whh;
  const float* bhh;
  float* c;
  const float* h_in;
  float* h_out;
  int xg_stride;
};

__global__ __launch_bounds__(256)
void slstm_step(StepInst I0, StepInst I1, int t) {
  __shared__ float hs[4 * H_DIM];
  __shared__ float gred[32][4];
  StepInst I = (blockIdx.x < 64) ? I0 : I1;
  rec_core(blockIdx.x & 63, t, threadIdx.x, I.xg, I.xg_stride, I.Whh, I.bhh,
           I.h_in, I.h_out, I.c, nullptr, nullptr, hs, gred);
}

// ---------------- pipelined decoder slot (5 roles, r7/r9-proven) ----------------
struct DecArgs {
  const float* xg0;
  float*       xg1;
  const unsigned short* Whh0bf; const unsigned short* Whh1bf;
  const float* bhh0; const float* bhh1;
  const unsigned short* Wih1bf; const float* bih1;
  const float* fc0W; const float* fc0b;
  const float* fc1W; const float* fc1b;
  const float* dyt_a;
  const float* dyt_g;
  const float* dyt_b;
  const float* thr0; const float* thr1;
  float* c0; float* c1;
  const float* h0_init; const float* h1_init;
  float* ring0; float* ring1;
  float* spk0; float* spk1;
  float* x1;
  unsigned short* x2;
};

__device__ __forceinline__ void stage_rows(const float* __restrict__ src, int t,
                                           int tid, float* dst) {
  float4* d4 = (float4*)dst;
  const int f0 = tid, f1 = tid + 256;
  d4[f0] = *(const float4*)(src + (size_t)((f0 >> 7) * S_LEN + t) * H_DIM + (f0 & 127) * 4);
  d4[f1] = *(const float4*)(src + (size_t)((f1 >> 7) * S_LEN + t) * H_DIM + (f1 & 127) * 4);
}

__global__ __launch_bounds__(256)
void dec_slot(DecArgs A, int s) {
  __shared__ float hs[4 * H_DIM];
  __shared__ float gred[32][4];
  const int bid = blockIdx.x;
  const int tid = threadIdx.x;

  if (bid < 64) {
    const int t = s;
    if (t < 256) {
      const float* h_in = (t == 0) ? A.h0_init : (A.ring0 + (size_t)(t & 1) * 2048);
      float* h_out = A.ring0 + (size_t)((t + 1) & 1) * 2048;
      rec_core(bid, t, tid, A.xg0, 2048, A.Whh0bf, A.bhh0, h_in, h_out, A.c0,
               A.spk0, A.thr0, hs, gred);
    }
  } else if (bid < 128) {
    const int t = s - 3;
    if (t >= 0 && t < 256) {
      const float* h_in = (t == 0) ? A.h1_init : (A.ring1 + (size_t)(t & 1) * 2048);
      float* h_out = A.ring1 + (size_t)((t + 1) & 1) * 2048;
      rec_core(bid - 64, t, tid, A.xg1, 2048, A.Whh1bf, A.bhh1, h_in, h_out, A.c1,
               A.spk1, A.thr1, hs, gred);
    }
  } else if (bid < 192) {
    const int t = s - 2;
    if (t >= 0 && t < 256) {
      stage_rows(A.x1, t, tid, hs);
      __syncthreads();
      const int wc = bid - 128;
      const int lr = tid >> 3, kc = tid & 7;
      const int row = wc * 32 + lr;
      const unsigned short* wrow = A.Wih1bf + (size_t)row * H_DIM;
      float acc[4] = {0.f, 0.f, 0.f, 0.f};
#pragma unroll
      for (int it = 0; it < 8; ++it) {
        const int k = it * 64 + kc * 8;
        const u16x8 wv = *(const u16x8*)(wrow + k);
        const float w0 = bf2f(wv[0]), w1 = bf2f(wv[1]), w2 = bf2f(wv[2]), w3 = bf2f(wv[3]);
        const float w4 = bf2f(wv[4]), w5 = bf2f(wv[5]), w6 = bf2f(wv[6]), w7 = bf2f(wv[7]);
#pragma unroll
        for (int b = 0; b < 4; ++b) {
          const float4 hA = *(const float4*)&hs[b * H_DIM + k];
          const float4 hB = *(const float4*)&hs[b * H_DIM + k + 4];
          acc[b] += w0 * hA.x + w1 * hA.y + w2 * hA.z + w3 * hA.w
                  + w4 * hB.x + w5 * hB.y + w6 * hB.z + w7 * hB.w;
        }
      }
#pragma unroll
      for (int off = 1; off < 8; off <<= 1) {
#pragma unroll
        for (int b = 0; b < 4; ++b) acc[b] += __shfl_xor(acc[b], off);
      }
      if (kc == 0) {
        const float bb = A.bih1[row];
#pragma unroll
        for (int b = 0; b < 4; ++b)
          A.xg1[(size_t)(b * S_LEN + t) * 2048 + row] = acc[b] + bb;
      }
    }
  } else {
    const bool isB = (bid < 224);
    const int t = isB ? (s - 1) : (s - 4);
    if (t >= 0 && t < 256) {
      const float* spk = isB ? A.spk0 : A.spk1;
      const float* fcW = isB ? A.fc0W : A.fc1W;
      const float* fcb = isB ? A.fc0b : A.fc1b;
      const int lidx = isB ? 0 : 1;
      stage_rows(spk, t, tid, hs);
      __syncthreads();
      const int wb = bid - (isB ? 192 : 224);
      const int lr = tid >> 4, kc = tid & 15;
      const int col = wb * 16 + lr;
      const float* wrow = fcW + (size_t)col * H_DIM;
      float a0 = 0.f, a1 = 0.f, a2 = 0.f, a3 = 0.f;
#pragma unroll
      for (int it = 0; it < 8; ++it) {
        const int k = kc * 32 + it * 4;
        const float4 w  = *(const float4*)(wrow + k);
        const float4 h0 = *(const float4*)&hs[0 * H_DIM + k];
        const float4 h1 = *(const float4*)&hs[1 * H_DIM + k];
        const float4 h2 = *(const float4*)&hs[2 * H_DIM + k];
        const float4 h3 = *(const float4*)&hs[3 * H_DIM + k];
        a0 += w.x * h0.x + w.y * h0.y + w.z * h0.z + w.w * h0.w;
        a1 += w.x * h1.x + w.y * h1.y + w.z * h1.z + w.w * h1.w;
        a2 += w.x * h2.x + w.y * h2.y + w.z * h2.z + w.w * h2.w;
        a3 += w.x * h3.x + w.y * h3.y + w.z * h3.z + w.w * h3.w;
      }
#pragma unroll
      for (int off = 1; off < 16; off <<= 1) {
        a0 += __shfl_xor(a0, off);
        a1 += __shfl_xor(a1, off);
        a2 += __shfl_xor(a2, off);
        a3 += __shfl_xor(a3, off);
      }
      if (kc == 0) {
        const float al = A.dyt_a[lidx];
        const float gm = A.dyt_g[lidx * H_DIM + col];
        const float be = A.dyt_b[lidx * H_DIM + col];
        const float bb = fcb[col];
        float v[4] = {a0, a1, a2, a3};
#pragma unroll
        for (int b = 0; b < 4; ++b) {
          float y = v[b] + bb;
          if (!isB) y += A.x1[(size_t)(b * S_LEN + t) * H_DIM + col];
          const float r = gm * tanhf(al * y) + be;
          if (isB) A.x1[(size_t)(b * S_LEN + t) * H_DIM + col] = r;
          else     A.x2[(size_t)(b * S_LEN + t) * H_DIM + col] = cvt_bf16(r);
        }
      }
    }
  }
}

extern "C" void kernel_launch(void* const* d_in, const int* in_sizes, int n_in,
                              void* d_out, int out_size, void* d_ws, size_t ws_size,
                              hipStream_t stream) {
  (void)in_sizes; (void)n_in; (void)out_size; (void)ws_size;
  const int*   src       = (const int*)d_in[0];
  const int*   tgt       = (const int*)d_in[1];
  const float* emb_enc   = (const float*)d_in[2];
  const float* enc_alpha = (const float*)d_in[3];
  const float* enc_gamma = (const float*)d_in[4];
  const float* enc_beta  = (const float*)d_in[5];
  const float* enc_Wih   = (const float*)d_in[6];
  const float* enc_Whh   = (const float*)d_in[7];
  const float* enc_bih   = (const float*)d_in[8];
  const float* enc_bhh   = (const float*)d_in[9];
  const float* emb_dec   = (const float*)d_in[11];
  const float* dec_alpha = (const float*)d_in[12];
  const float* dec_gamma = (const float*)d_in[13];
  const float* dec_beta  = (const float*)d_in[14];
  const float* dec_Wih   = (const float*)d_in[15];
  const float* dec_Whh   = (const float*)d_in[16];
  const float* dec_bih   = (const float*)d_in[17];
  const float* dec_bhh   = (const float*)d_in[18];
  const float* dec_thr   = (const float*)d_in[19];
  const float* dec_fc_W  = (const float*)d_in[20];
  const float* dec_fc_b  = (const float*)d_in[21];
  const float* dyt_alpha = (const float*)d_in[22];
  const float* dyt_gamma = (const float*)d_in[23];
  const float* dyt_beta  = (const float*)d_in[24];
  const float* out_W     = (const float*)d_in[25];
  const float* out_b     = (const float*)d_in[26];
  float* out = (float*)d_out;

  float* ws = (float*)d_ws;
  float*          x1        = ws;                                 // [1024,512] f32
  float*          xg_enc    = ws + 524288;                        // [1024,4096] f32
  float*          xg_d0     = xg_enc;                             // overlay after enc
  float*          xg_d1     = xg_enc + 2097152;                   // [1024,2048]
  float*          spk0      = ws + 4718592;                       // [1024,512]
  float*          spk1      = ws + 5242880;                       // [1024,512]
  unsigned short* src_e_bf  = (unsigned short*)(ws + 5767168);    // [1024,512] bf16
  unsigned short* dec_x0_bf = (unsigned short*)(ws + 5898240);    // [1024,512] bf16
  unsigned short* x2_bf     = (unsigned short*)(ws + 6029312);    // [1024,512] bf16
  unsigned short* wbf       = (unsigned short*)(ws + 6160384);    // up to 3M bf16
  float* st = ws + 7660544;
  float* zbuf    = st;                       // [2048] zeros
  float* c0buf   = st + 2048;
  float* c1buf   = st + 4096;
  float* ring_e0 = st + 6144;                // [2][2048]
  float* ring_e1 = st + 10240;
  float* ring_d0 = st + 14336;
  float* ring_d1 = st + 18432;               // end st+22528

  zero_kernel<<<6, 256, 0, stream>>>(st, 1536);   // zbuf + c0 + c1
  embed_dyt<<<1024, 128, 0, stream>>>(src, emb_enc, enc_alpha, enc_gamma, enc_beta,
                                      src_e_bf);
  embed_dyt<<<1024, 128, 0, stream>>>(tgt, emb_dec, dec_alpha, dec_gamma, dec_beta,
                                      dec_x0_bf);

  // enc Whh (both layers, [2,2048,512]) -> bf16
  cvt_f32_bf16<<<2048, 256, 0, stream>>>(enc_Whh, wbf, 524288);

  // Encoder xg (both layers stacked [4096,512]) via bf16 MFMA
  gemm_bt_bf16<0><<<dim3(8, 32), 256, 0, stream>>>(src_e_bf, enc_Wih, enc_bih,
                                                   xg_enc, 4096, 512);

  // Encoder recurrence: 256 per-step dispatches, both layers each
  for (int t = 0; t < 256; ++t) {
    StepInst A, B;
    A.xg = xg_enc;        A.Whh = wbf;                A.bhh = enc_bhh;
    A.c = c0buf;
    A.h_in  = (t == 0) ? zbuf : ring_e0 + (t & 1) * 2048;
    A.h_out = ring_e0 + ((t + 1) & 1) * 2048;
    A.xg_stride = 4096;
    B.xg = xg_enc + 2048; B.Whh = wbf + 1048576;      B.bhh = enc_bhh + 2048;
    B.c = c1buf;
    B.h_in  = (t == 0) ? zbuf : ring_e1 + (t & 1) * 2048;
    B.h_out = ring_e1 + ((t + 1) & 1) * 2048;
    B.xg_stride = 4096;
    slstm_step<<<128, 256, 0, stream>>>(A, B, t);
  }

  // dec weights -> bf16 in ONE dispatch (Whh both layers + Wih layer1)
  cvt_f32_bf16_2<<<3072, 256, 0, stream>>>(dec_Whh, wbf, 524288,
                                           dec_Wih + 1048576, wbf + 2097152, 262144);

  // Decoder layer0 xg via bf16 MFMA (overwrites xg_enc region)
  gemm_bt_bf16<0><<<dim3(8, 16), 256, 0, stream>>>(dec_x0_bf, dec_Wih, dec_bih,
                                                   xg_d0, 2048, 512);

  DecArgs D;
  D.xg0 = xg_d0;              D.xg1 = xg_d1;
  D.Whh0bf = wbf;             D.Whh1bf = wbf + 1048576;
  D.bhh0 = dec_bhh;           D.bhh1 = dec_bhh + 2048;
  D.Wih1bf = wbf + 2097152;   D.bih1 = dec_bih + 2048;
  D.fc0W = dec_fc_W;          D.fc0b = dec_fc_b;
  D.fc1W = dec_fc_W + 262144; D.fc1b = dec_fc_b + 512;
  D.dyt_a = dyt_alpha;        D.dyt_g = dyt_gamma;     D.dyt_b = dyt_beta;
  D.thr0 = dec_thr;           D.thr1 = dec_thr + 512;
  D.c0 = c0buf;               D.c1 = c1buf;
  D.h0_init = ring_e0;        D.h1_init = ring_e1;     // parity-0 halves
  D.ring0 = ring_d0;          D.ring1 = ring_d1;
  D.spk0 = spk0;              D.spk1 = spk1;
  D.x1 = x1;                  D.x2 = x2_bf;

  for (int s = 0; s < 260; ++s)
    dec_slot<<<256, 256, 0, stream>>>(D, s);

  // Output projection with exact A-tile zero-skip
  gemm_bt_bf16<1><<<dim3(8, 250), 256, 0, stream>>>(x2_bf, out_W, out_b,
                                                    out, 32000, 512);
}